// Round 1
// baseline (292.635 us; speedup 1.0000x reference)
//
#include <hip/hip_runtime.h>

typedef __attribute__((ext_vector_type(4))) float f32x4;
typedef __attribute__((ext_vector_type(8))) short bf16x8;

#define SEQ    2048
#define HD     64
#define NBH    32      // B*H
#define MTOK   4096    // B*S
#define DMODEL 1024

__device__ __forceinline__ unsigned short f2b(float f) {
  unsigned int u = __float_as_uint(f);
  u += 0x7fffu + ((u >> 16) & 1u);
  return (unsigned short)(u >> 16);
}
__device__ __forceinline__ float b2f(unsigned short s) {
  return __uint_as_float(((unsigned int)s) << 16);
}
__device__ __forceinline__ void gload16(const void* g, void* l) {
  __builtin_amdgcn_global_load_lds(
      (const __attribute__((address_space(1))) unsigned int*)g,
      (__attribute__((address_space(3))) unsigned int*)l, 16, 0, 0);
}

// ---------- x f32 -> bf16 ----------
__global__ __launch_bounds__(256) void k_convert_x(const float* __restrict__ x,
                                                   unsigned short* __restrict__ xb) {
  int i = blockIdx.x * 256 + threadIdx.x;
  float4 v = ((const float4*)x)[i];
  ushort4 o;
  o.x = f2b(v.x); o.y = f2b(v.y); o.z = f2b(v.z); o.w = f2b(v.w);
  ((ushort4*)xb)[i] = o;
}

// ---------- W [K=1024][N=1024] f32 -> Wt [N][K] bf16 ----------
__global__ __launch_bounds__(256) void k_wtrans(const float* __restrict__ W,
                                                unsigned short* __restrict__ Wt) {
  __shared__ float tile[64 * 65];
  int bi = blockIdx.x, bj = blockIdx.y, t = threadIdx.x;
  for (int p = 0; p < 16; p++) {
    int e = p * 256 + t;
    int r = e >> 6, c = e & 63;
    tile[r * 65 + c] = W[(size_t)(bi * 64 + r) * DMODEL + bj * 64 + c];
  }
  __syncthreads();
  for (int p = 0; p < 16; p++) {
    int e = p * 256 + t;
    int n = e >> 6, k = e & 63;
    Wt[(size_t)(bj * 64 + n) * DMODEL + bi * 64 + k] = f2b(tile[k * 65 + n]);
  }
}

// ---------- GEMM C = A[M,K] * Bt[N,K]^T, 128x128 tile, BK=64 ----------
// MODE 0: Cf[row*N+col] = acc + bias0[col]   (f32 out)
// MODE 1: QKV split: col -> which(Q/K/V), write bf16 [B,H,S,hd] + bias
template <int MODE>
__global__ __launch_bounds__(256) void k_gemm_bt(
    const unsigned short* __restrict__ A, const unsigned short* __restrict__ Bt,
    int M, int N, int K,
    const float* __restrict__ bias0, const float* __restrict__ bias1,
    const float* __restrict__ bias2,
    float* __restrict__ Cf,
    unsigned short* __restrict__ Qo, unsigned short* __restrict__ Ko,
    unsigned short* __restrict__ Vo) {
  __shared__ unsigned short As[128 * 64];
  __shared__ unsigned short Bs[128 * 64];
  int bm = blockIdx.x, bn = blockIdx.y;
  int tid = threadIdx.x;
  int w = tid >> 6, lane = tid & 63;
  int lg = lane >> 4, lc = lane & 15;
  int wm = (w >> 1) * 64, wn = (w & 1) * 64;
  f32x4 acc[4][4];
  for (int a = 0; a < 4; a++)
    for (int b = 0; b < 4; b++) acc[a][b] = (f32x4){0.f, 0.f, 0.f, 0.f};
  const unsigned short* ag = A + (size_t)(bm * 128) * K;
  const unsigned short* bg = Bt + (size_t)(bn * 128) * K;
  for (int k0 = 0; k0 < K; k0 += 64) {
    __syncthreads();
    for (int p = 0; p < 4; p++) {
      int c = (w * 4 + p) * 64 + lane;
      int r = c >> 3, col = (c & 7) * 8;
      gload16(ag + (size_t)r * K + k0 + col, &As[(w * 4 + p) * 512]);
      gload16(bg + (size_t)r * K + k0 + col, &Bs[(w * 4 + p) * 512]);
    }
    __syncthreads();
    for (int kk = 0; kk < 2; kk++) {
      bf16x8 av[4], bv[4];
      for (int mi = 0; mi < 4; mi++)
        av[mi] = *(const bf16x8*)&As[(wm + mi * 16 + lc) * 64 + kk * 32 + lg * 8];
      for (int ni = 0; ni < 4; ni++)
        bv[ni] = *(const bf16x8*)&Bs[(wn + ni * 16 + lc) * 64 + kk * 32 + lg * 8];
      for (int mi = 0; mi < 4; mi++)
        for (int ni = 0; ni < 4; ni++)
          acc[mi][ni] = __builtin_amdgcn_mfma_f32_16x16x32_bf16(av[mi], bv[ni], acc[mi][ni], 0, 0, 0);
    }
  }
  for (int mi = 0; mi < 4; mi++) {
    for (int i = 0; i < 4; i++) {
      int row = bm * 128 + wm + mi * 16 + 4 * lg + i;
      for (int ni = 0; ni < 4; ni++) {
        int col = bn * 128 + wn + ni * 16 + lc;
        float v = acc[mi][ni][i];
        if (MODE == 0) {
          Cf[(size_t)row * N + col] = v + bias0[col];
        } else {
          int which = col >> 10, hcol = col & 1023;
          const float* bb = which == 0 ? bias0 : (which == 1 ? bias1 : bias2);
          unsigned short* dst = which == 0 ? Qo : (which == 1 ? Ko : Vo);
          int b = row >> 11, s = row & 2047;
          int h = hcol >> 6, d = hcol & 63;
          dst[(((size_t)(b * 16 + h)) * SEQ + s) * HD + d] = f2b(v + bb[hcol]);
        }
      }
    }
  }
}

// ---------- V [bh][S][hd] -> Vt [bh][hd][S] ----------
__global__ __launch_bounds__(256) void k_transpose_v(const unsigned short* __restrict__ V,
                                                     unsigned short* __restrict__ Vt) {
  __shared__ unsigned short tile[64 * 72];
  int sc = blockIdx.x, bh = blockIdx.y, t = threadIdx.x;
  int s0 = sc * 64;
  for (int p = 0; p < 16; p++) {
    int e = p * 256 + t;
    int r = e >> 6, c = e & 63;
    tile[r * 72 + c] = V[(((size_t)bh) * SEQ + s0 + r) * HD + c];
  }
  __syncthreads();
  for (int p = 0; p < 16; p++) {
    int e = p * 256 + t;
    int d = e >> 6, j = e & 63;
    Vt[(((size_t)bh) * HD + d) * SEQ + s0 + j] = tile[j * 72 + d];
  }
}

// ---------- qr[bh][s][r] = Q[bh][s][:] . rel_emb[r][:] ----------
__global__ __launch_bounds__(256) void k_qr(const unsigned short* __restrict__ Qb,
                                            const float* __restrict__ rel_emb,
                                            float* __restrict__ qr) {
  __shared__ float relS[65 * 66];
  __shared__ unsigned short qS[32 * 64];
  int sc = blockIdx.x, bh = blockIdx.y, t = threadIdx.x;
  int s0 = sc * 32;
  for (int i = t; i < 65 * 64; i += 256) relS[(i >> 6) * 66 + (i & 63)] = rel_emb[i];
  for (int i = t; i < 32 * 64; i += 256) qS[i] = Qb[((size_t)bh * SEQ + s0) * HD + i];
  __syncthreads();
  for (int e = t; e < 32 * 65; e += 256) {
    int sl = e / 65, r = e % 65;
    float acc = 0.f;
    for (int d = 0; d < 64; d++) acc += b2f(qS[sl * 64 + d]) * relS[r * 66 + d];
    qr[((size_t)bh * SEQ + s0 + sl) * 65 + r] = acc;
  }
}

// ---------- flash attention with relative bias ----------
__global__ __launch_bounds__(256) void k_attn(const unsigned short* __restrict__ Qb,
                                              const unsigned short* __restrict__ Kb,
                                              const unsigned short* __restrict__ Vtb,
                                              const float* __restrict__ qr,
                                              unsigned short* __restrict__ ctx) {
  __shared__ unsigned short Ks[64 * 64];
  __shared__ unsigned short Vts[64 * 64];
  __shared__ unsigned short Ps[4 * 16 * 64];
  __shared__ float qrs[64 * 65];
  int bh = blockIdx.x, qt = blockIdx.y;
  int tid = threadIdx.x, w = tid >> 6, lane = tid & 63;
  int lg = lane >> 4, lc = lane & 15;
  int q0 = qt * 64, qw = q0 + w * 16;

  {
    const float* src = qr + ((size_t)bh * SEQ + q0) * 65;
    for (int i = tid; i < 64 * 65; i += 256) qrs[i] = src[i];
  }
  bf16x8 aq[2];
  {
    const unsigned short* qp = Qb + ((size_t)bh * SEQ + qw + lc) * HD + lg * 8;
    aq[0] = *(const bf16x8*)qp;
    aq[1] = *(const bf16x8*)(qp + 32);
  }
  f32x4 o[4];
  float m[4], l[4], fac[4];
  for (int n = 0; n < 4; n++) o[n] = (f32x4){0.f, 0.f, 0.f, 0.f};
  for (int i = 0; i < 4; i++) { m[i] = -1e30f; l[i] = 0.f; }
  __syncthreads();

  for (int kt = 0; kt < SEQ / 64; kt++) {
    int k0 = kt * 64;
    const unsigned short* kg = Kb + ((size_t)bh * SEQ + k0) * HD;
    const unsigned short* vg = Vtb + ((size_t)bh * HD) * SEQ + k0;
    for (int p = 0; p < 2; p++) {
      int c = (w * 2 + p) * 64 + lane;
      int r = c >> 3, col = (c & 7) * 8;
      gload16(kg + (size_t)r * HD + col, &Ks[(w * 2 + p) * 512]);
      gload16(vg + (size_t)r * SEQ + col, &Vts[(w * 2 + p) * 512]);
    }
    __syncthreads();

    f32x4 s[4];
    for (int n = 0; n < 4; n++) {
      s[n] = (f32x4){0.f, 0.f, 0.f, 0.f};
      for (int kk = 0; kk < 2; kk++) {
        bf16x8 bk = *(const bf16x8*)&Ks[(n * 16 + lc) * 64 + kk * 32 + lg * 8];
        s[n] = __builtin_amdgcn_mfma_f32_16x16x32_bf16(aq[kk], bk, s[n], 0, 0, 0);
      }
    }
    float sv[4][4];
    for (int n = 0; n < 4; n++)
      for (int i = 0; i < 4; i++) {
        int ql = w * 16 + 4 * lg + i;
        int rel = (q0 + ql) - (k0 + n * 16 + lc);
        rel = rel < -32 ? -32 : (rel > 32 ? 32 : rel);
        sv[n][i] = 0.125f * (s[n][i] + qrs[ql * 65 + rel + 32]);
      }
    for (int i = 0; i < 4; i++) {
      float tm = fmaxf(fmaxf(sv[0][i], sv[1][i]), fmaxf(sv[2][i], sv[3][i]));
      tm = fmaxf(tm, __shfl_xor(tm, 1));
      tm = fmaxf(tm, __shfl_xor(tm, 2));
      tm = fmaxf(tm, __shfl_xor(tm, 4));
      tm = fmaxf(tm, __shfl_xor(tm, 8));
      float mn = fmaxf(m[i], tm);
      fac[i] = __expf(m[i] - mn);
      m[i] = mn;
      float ts = 0.f;
      for (int n = 0; n < 4; n++) {
        float pv = __expf(sv[n][i] - mn);
        sv[n][i] = pv;
        ts += pv;
      }
      ts += __shfl_xor(ts, 1);
      ts += __shfl_xor(ts, 2);
      ts += __shfl_xor(ts, 4);
      ts += __shfl_xor(ts, 8);
      l[i] = l[i] * fac[i] + ts;
    }
    for (int n = 0; n < 4; n++)
      for (int i = 0; i < 4; i++) o[n][i] *= fac[i];
    for (int n = 0; n < 4; n++)
      for (int i = 0; i < 4; i++)
        Ps[w * 1024 + (4 * lg + i) * 64 + n * 16 + lc] = f2b(sv[n][i]);
    for (int kk = 0; kk < 2; kk++) {
      bf16x8 ap = *(const bf16x8*)&Ps[w * 1024 + lc * 64 + kk * 32 + lg * 8];
      for (int n = 0; n < 4; n++) {
        bf16x8 bv = *(const bf16x8*)&Vts[(n * 16 + lc) * 64 + kk * 32 + lg * 8];
        o[n] = __builtin_amdgcn_mfma_f32_16x16x32_bf16(ap, bv, o[n], 0, 0, 0);
      }
    }
    __syncthreads();
  }
  int b = bh >> 4, h = bh & 15;
  for (int i = 0; i < 4; i++) {
    float inv = 1.f / l[i];
    int qg = q0 + w * 16 + 4 * lg + i;
    size_t base = ((size_t)(b * SEQ + qg)) * DMODEL + h * HD;
    for (int n = 0; n < 4; n++) ctx[base + n * 16 + lc] = f2b(o[n][i] * inv);
  }
}

extern "C" void kernel_launch(void* const* d_in, const int* in_sizes, int n_in,
                              void* d_out, int out_size, void* d_ws, size_t ws_size,
                              hipStream_t stream) {
  const float* x   = (const float*)d_in[0];
  const float* Wq  = (const float*)d_in[1];
  const float* bq  = (const float*)d_in[2];
  const float* Wk  = (const float*)d_in[3];
  const float* bk  = (const float*)d_in[4];
  const float* Wv  = (const float*)d_in[5];
  const float* bv  = (const float*)d_in[6];
  const float* Wo  = (const float*)d_in[7];
  const float* bo  = (const float*)d_in[8];
  const float* rel = (const float*)d_in[9];
  float* out = (float*)d_out;

  char* ws = (char*)d_ws;
  size_t off = 0;
  auto carve = [&](size_t bytes) -> void* {
    void* p = ws + off;
    off += (bytes + 255) & ~(size_t)255;
    return p;
  };
  unsigned short* xb   = (unsigned short*)carve((size_t)MTOK * DMODEL * 2);
  unsigned short* Wqkv = (unsigned short*)carve((size_t)3 * DMODEL * DMODEL * 2);
  unsigned short* Wot  = (unsigned short*)carve((size_t)DMODEL * DMODEL * 2);
  unsigned short* Qb   = (unsigned short*)carve((size_t)NBH * SEQ * HD * 2);
  unsigned short* Kb   = (unsigned short*)carve((size_t)NBH * SEQ * HD * 2);
  unsigned short* Vb   = (unsigned short*)carve((size_t)NBH * SEQ * HD * 2);
  unsigned short* Vtb  = (unsigned short*)carve((size_t)NBH * SEQ * HD * 2);
  float*          qr   = (float*)carve((size_t)NBH * SEQ * 65 * 4);
  unsigned short* ctx  = (unsigned short*)carve((size_t)MTOK * DMODEL * 2);

  k_convert_x<<<MTOK * DMODEL / 4 / 256, 256, 0, stream>>>(x, xb);
  k_wtrans<<<dim3(16, 16), 256, 0, stream>>>(Wq, Wqkv);
  k_wtrans<<<dim3(16, 16), 256, 0, stream>>>(Wk, Wqkv + (size_t)DMODEL * DMODEL);
  k_wtrans<<<dim3(16, 16), 256, 0, stream>>>(Wv, Wqkv + (size_t)2 * DMODEL * DMODEL);
  k_wtrans<<<dim3(16, 16), 256, 0, stream>>>(Wo, Wot);
  k_gemm_bt<1><<<dim3(32, 24), 256, 0, stream>>>(xb, Wqkv, MTOK, 3 * DMODEL, DMODEL,
                                                 bq, bk, bv, nullptr, Qb, Kb, Vb);
  k_transpose_v<<<dim3(32, 32), 256, 0, stream>>>(Vb, Vtb);
  k_qr<<<dim3(64, 32), 256, 0, stream>>>(Qb, rel, qr);
  k_attn<<<dim3(32, 32), 256, 0, stream>>>(Qb, Kb, Vtb, qr, ctx);
  k_gemm_bt<0><<<dim3(32, 8), 256, 0, stream>>>(ctx, Wot, MTOK, DMODEL, DMODEL,
                                                bo, nullptr, nullptr, out,
                                                nullptr, nullptr, nullptr);
}